// Round 2
// baseline (2896.622 us; speedup 1.0000x reference)
//
#include <hip/hip_runtime.h>

// ---------------------------------------------------------------------------
// Problem constants
// ---------------------------------------------------------------------------
constexpr int CT = 32;      // T
constexpr int CN = 64;      // N
constexpr int CE = 256;     // E = DOBS*V
constexpr int CHID = 1024;
constexpr int CA = 32;      // num options
constexpr int CS = 32;      // planning steps
constexpr int CHP = 8;      // planning horizon
constexpr int TN = CT * CN; // 2048

// d_out float offsets (return order: search_logits, planned_actions, X, value,
// model_loss, embed_loss)
constexpr size_t O_SL  = 0;        // 32*64*32 = 65536
constexpr size_t O_PA  = 65536;    // 64*8     = 512
constexpr size_t O_X   = 66048;    // 64*8*256 = 131072
constexpr size_t O_VAL = 197120;   // 32*64    = 2048
constexpr size_t O_ML  = 199168;   // 32*64*256= 524288
constexpr size_t O_EL  = 723456;   // 32*64    = 2048

// ws byte offsets (~100 MB total)
constexpr size_t B_EMB    = 0;                           // 2 MB   [2048][256] f32
constexpr size_t B_H1     = 2u * 1024 * 1024;            // 256 KB [64][1024]
constexpr size_t B_XS     = B_H1 + 256 * 1024;           // 128 KB [64][512]
constexpr size_t B_PART   = B_XS + 128 * 1024;           // 512 KB [64][8][256]
constexpr size_t B_LOG    = 3u * 1024 * 1024;            // 8 KB   [64][32]
constexpr size_t B_IBUF   = B_LOG + 8 * 1024;
constexpr size_t B_IUP    = B_IBUF + 1024;
constexpr size_t B_PUSH   = B_IUP + 1024;
constexpr size_t B_BAR    = B_PUSH + 1024;
constexpr size_t B_CNT    = B_LOG + 16 * 1024;           // 33*32 ints
constexpr size_t B_LISTS  = B_LOG + 32 * 1024;           // 32*32*64 ints = 256 KB
constexpr size_t B_CNTTL  = B_LOG + 384 * 1024;          // 32 ints
constexpr size_t B_LISTTL = B_CNTTL + 1024;              // 32 KB [32][256]
// 32MB+ multi-phase region: We2T (early) -> Wm1T (mid) -> xstl/hbig/parttl/Wm2T
constexpr size_t B_R32    = 4u * 1024 * 1024;
constexpr size_t B_WE2T   = B_R32;                       // 1 MB  (dead after x0)
constexpr size_t B_WM1T   = B_R32;                       // 32 MB (dead after wpm)
constexpr size_t B_XSTL   = B_R32;                       // 4 MB  [2048][512]
constexpr size_t B_HBIG   = B_R32 + 4u * 1024 * 1024;    // 8 MB  [2048][1024]
constexpr size_t B_PARTTL = B_R32 + 12u * 1024 * 1024;   // 16 MB [2048][8][256]
constexpr size_t B_WM2T   = B_R32 + 28u * 1024 * 1024;   // 1 MB  [1024][256]
constexpr size_t B_WPM    = B_R32 + 32u * 1024 * 1024;   // 64 MB [32][512][1024]

__device__ __forceinline__ void fma4(float4& a, float s, const float4& w) {
  a.x = fmaf(s, w.x, a.x); a.y = fmaf(s, w.y, a.y);
  a.z = fmaf(s, w.z, a.z); a.w = fmaf(s, w.w, a.w);
}

// ---------------------------------------------------------------------------
// init: zero PA+X span of d_out, logits, per-step cnt, tl cnt, barrier
// ---------------------------------------------------------------------------
__global__ void init_kernel(float* __restrict__ out, float* __restrict__ logits,
                            int* __restrict__ cnt, int* __restrict__ cnt_tl,
                            int* __restrict__ bar) {
  int idx = blockIdx.x * 256 + threadIdx.x;
  if (idx < 131584) out[O_PA + idx] = 0.f;  // PA (512) + X (131072) contiguous
  if (idx < CN * CA) logits[idx] = 0.f;
  if (idx < 33 * CA) cnt[idx] = 0;
  if (idx < CA) cnt_tl[idx] = 0;
  if (idx < 2) bar[idx] = 0;
}

// ---------------------------------------------------------------------------
// emb[t][n][e] = embed1[obs[t][n][e>>4]][e&15]
// ---------------------------------------------------------------------------
__global__ void emb_kernel(const int* __restrict__ obs, const float* __restrict__ embed1,
                           float* __restrict__ emb) {
  int idx = blockIdx.x * 256 + threadIdx.x;
  int b = idx >> 5, k8 = idx & 31;
  int e0 = k8 * 8;
  int d = e0 >> 4;
  int o = obs[b * 16 + d];
  const float* src = embed1 + o * 16 + (e0 & 15);
  float4 v0 = *(const float4*)src;
  float4 v1 = *(const float4*)(src + 4);
  float* dst = emb + (size_t)b * CE + e0;
  *(float4*)dst = v0;
  *(float4*)(dst + 4) = v1;
}

// ---------------------------------------------------------------------------
// One GRU step with h0 = 0 (only Hs[0] used downstream; Whh provably unused)
// ---------------------------------------------------------------------------
__global__ void h1_kernel(const float* __restrict__ emb, const float* __restrict__ Wih,
                          const float* __restrict__ bih, const float* __restrict__ bhh,
                          float* __restrict__ h1) {
  int t = threadIdx.x, bid = blockIdx.x;   // 256 blocks of (64n x 4j)
  int n = t & 63, j = bid * 4 + (t >> 6);
  const float* x = emb + (size_t)n * CE;   // emb[0] rows
  const float* wr = Wih + (size_t)j * CE;
  const float* wz = Wih + (size_t)(CHID + j) * CE;
  const float* wn = Wih + (size_t)(2 * CHID + j) * CE;
  float ar = 0.f, az = 0.f, an = 0.f;
  #pragma unroll 4
  for (int e = 0; e < CE; ++e) {
    float xe = x[e];
    ar += xe * wr[e]; az += xe * wz[e]; an += xe * wn[e];
  }
  ar += bih[j] + bhh[j];
  az += bih[CHID + j] + bhh[CHID + j];
  float r = 1.f / (1.f + expf(-ar));
  float z = 1.f / (1.f + expf(-az));
  float nn = tanhf(an + bih[2 * CHID + j] + r * bhh[2 * CHID + j]);
  h1[(size_t)n * CHID + j] = (1.f - z) * nn;
}

// ---------------------------------------------------------------------------
// Generic 64x64 tiled transpose: in[R][C] -> out[C][R]
// ---------------------------------------------------------------------------
__global__ void trans_kernel(const float* __restrict__ in, float* __restrict__ out,
                             int R, int C) {
  __shared__ float tile[64][65];
  int tj = threadIdx.x & 63, tg = threadIdx.x >> 6;
  int cb = blockIdx.x * 64, rb = blockIdx.y * 64;
  #pragma unroll
  for (int i = 0; i < 16; ++i) {
    int r = tg * 16 + i;
    tile[r][tj] = in[(size_t)(rb + r) * C + cb + tj];
  }
  __syncthreads();
  #pragma unroll
  for (int i = 0; i < 16; ++i) {
    int c2 = tg * 16 + i;
    out[(size_t)(cb + c2) * R + rb + tj] = tile[tj][c2];
  }
}

// ---------------------------------------------------------------------------
// X[:,0] = h1 @ We2^T + be2   (We2T layout [k][e])
// ---------------------------------------------------------------------------
__global__ void x0_kernel(const float* __restrict__ h1, const float* __restrict__ We2T,
                          const float* __restrict__ be2, float* __restrict__ Xout) {
  int et = blockIdx.x, n = blockIdx.y, t = threadIdx.x;
  int el = t & 63, kq = t >> 6;
  __shared__ float hr[1024];
  __shared__ float sred2[4][64];
  for (int idx = t; idx < 1024; idx += 256) hr[idx] = h1[(size_t)n * CHID + idx];
  __syncthreads();
  int e = et * 64 + el;
  float acc = 0.f;
  for (int k = kq * 256; k < kq * 256 + 256; ++k) acc += hr[k] * We2T[(size_t)k * CE + e];
  sred2[kq][el] = acc;
  __syncthreads();
  if (t < 64) {
    float s2 = sred2[0][t] + sred2[1][t] + sred2[2][t] + sred2[3][t] + be2[et * 64 + t];
    Xout[(size_t)(n * CHP) * CE + et * 64 + t] = s2;
  }
}

// ---------------------------------------------------------------------------
// Factorized model weights:
// Wpm[o][e][j]     = sum_a relu( embed_opt[o][a]) * Wm1[j][a*256+e]
// Wpm[o][256+e][j] = sum_a relu(-embed_opt[o][a]) * Wm1[j][a*256+e]
// ---------------------------------------------------------------------------
__global__ void wpm_kernel(const float* __restrict__ Wm1T, const float* __restrict__ eo,
                           float* __restrict__ Wpm) {
  int e = blockIdx.x, jt = blockIdx.y, t = threadIdx.x;
  int j = jt * 256 + t;
  __shared__ float rp[CA * CA], rm[CA * CA];
  for (int idx = t; idx < CA * CA; idx += 256) {
    float v = eo[idx];
    rp[idx] = fmaxf(v, 0.f);
    rm[idx] = fmaxf(-v, 0.f);
  }
  __syncthreads();
  float w[32];
  #pragma unroll
  for (int a = 0; a < 32; ++a) w[a] = Wm1T[(size_t)(a * 256 + e) * CHID + j];
  for (int o = 0; o < 32; ++o) {
    float sp = 0.f, sm = 0.f;
    #pragma unroll
    for (int a = 0; a < 32; ++a) {
      float wa = w[a];
      sp += rp[o * 32 + a] * wa;
      sm += rm[o * 32 + a] * wa;
    }
    Wpm[((size_t)o * 512 + e) * CHID + j] = sp;
    Wpm[((size_t)o * 512 + 256 + e) * CHID + j] = sm;
  }
}

// ---------------------------------------------------------------------------
// Group time-loop rows by option (list order nondeterministic; results aren't)
// ---------------------------------------------------------------------------
__global__ void tllists_kernel(const int* __restrict__ P, int* __restrict__ cnt_tl,
                               int* __restrict__ list_tl) {
  int b = blockIdx.x * 256 + threadIdx.x;
  if (b >= TN) return;
  int a = P[b];
  int slot = atomicAdd(&cnt_tl[a], 1);
  list_tl[a * 256 + slot] = b;
}

// xs_tl[b][k] = relu(+/- prev[b][k&255]),  prev = emb shifted by one t (wrap)
__global__ void xstl_kernel(const float* __restrict__ emb, float* __restrict__ xs) {
  int idx = blockIdx.x * 256 + threadIdx.x;   // < 2048*512
  int b = idx >> 9, k = idx & 511;
  int e = k & 255;
  int bp = (b < CN) ? (b + (CT - 1) * CN) : (b - CN);
  float v = emb[(size_t)bp * CE + e];
  xs[idx] = (k < 256) ? fmaxf(v, 0.f) : fmaxf(-v, 0.f);
}

// ---------------------------------------------------------------------------
// Time-loop factorized model layer 1:
// h[row][j] = relu( sum_{k<512} xs[row][k] * Wpm[o][k][j] + bm1[j] )
// grid (32 o, 8 j-tiles of 128, z row-group start)
// ---------------------------------------------------------------------------
__global__ __launch_bounds__(256) void l1_kernel(
    const float* __restrict__ Wpm, const float* __restrict__ xs,
    const float* __restrict__ bm1, const int* __restrict__ cnt,
    const int* __restrict__ list, int listStride, float* __restrict__ hout) {
  int o = blockIdx.x, jt = blockIdx.y;
  int c = cnt[o];
  if (c <= 0) return;
  __shared__ __align__(16) float sbuf[8192];
  __shared__ int srows[8];
  int t = threadIdx.x;
  int jl = t & 31, kq = t >> 5;
  int jb = jt * 128;
  const float* wb = Wpm + (size_t)o * (512 * CHID) + jb + jl * 4;
  for (int g = blockIdx.z; g * 8 < c; g += gridDim.z) {
    int base = g * 8;
    int nr = min(8, c - base);
    if (t < 8) srows[t] = (t < nr) ? list[o * listStride + base + t] : -1;
    __syncthreads();
    for (int idx = t; idx < 4096; idx += 256) {
      int row = srows[idx >> 9];
      sbuf[idx] = (row >= 0) ? xs[(size_t)row * 512 + (idx & 511)] : 0.f;
    }
    __syncthreads();
    float4 acc[8];
    #pragma unroll
    for (int r = 0; r < 8; ++r) acc[r] = make_float4(0.f, 0.f, 0.f, 0.f);
    int kbase = kq * 64;
    for (int k4 = 0; k4 < 64; k4 += 4) {
      int k = kbase + k4;
      float4 w0 = *(const float4*)(wb + (size_t)(k + 0) * CHID);
      float4 w1 = *(const float4*)(wb + (size_t)(k + 1) * CHID);
      float4 w2 = *(const float4*)(wb + (size_t)(k + 2) * CHID);
      float4 w3 = *(const float4*)(wb + (size_t)(k + 3) * CHID);
      #pragma unroll
      for (int r = 0; r < 8; ++r) {
        float4 xv = *(const float4*)&sbuf[r * 512 + k];
        fma4(acc[r], xv.x, w0); fma4(acc[r], xv.y, w1);
        fma4(acc[r], xv.z, w2); fma4(acc[r], xv.w, w3);
      }
    }
    __syncthreads();
    #pragma unroll
    for (int r = 0; r < 8; ++r)
      *(float4*)&sbuf[(kq * 8 + r) * 128 + jl * 4] = acc[r];
    __syncthreads();
    for (int idx = t; idx < 1024; idx += 256) {
      int r = idx >> 7, jc = idx & 127;
      float s = 0.f;
      #pragma unroll
      for (int q = 0; q < 8; ++q) s += sbuf[(q * 8 + r) * 128 + jc];
      int row = srows[r];
      if (row >= 0)
        hout[(size_t)row * CHID + jb + jc] = fmaxf(s + bm1[jb + jc], 0.f);
    }
    __syncthreads();
  }
}

// ---------------------------------------------------------------------------
// Time-loop layer 2 partials: part[b][kq][e], 8 k-slices of 128
// grid (8 kq, 64 row-groups of 32), 256 thr (= e)
// ---------------------------------------------------------------------------
__global__ __launch_bounds__(256) void l2big_kernel(const float* __restrict__ h,
    const float* __restrict__ Wm2T, float* __restrict__ part) {
  int kq = blockIdx.x, rg = blockIdx.y, t = threadIdx.x;
  int rb = rg * 32, kb = kq * 128;
  __shared__ __align__(16) float hl[4096];
  for (int idx = t; idx < 4096; idx += 256)
    hl[idx] = h[(size_t)(rb + (idx >> 7)) * CHID + kb + (idx & 127)];
  __syncthreads();
  float acc[32];
  #pragma unroll
  for (int r = 0; r < 32; ++r) acc[r] = 0.f;
  for (int kk = 0; kk < 128; kk += 4) {
    float w0 = Wm2T[(size_t)(kb + kk + 0) * CE + t];
    float w1 = Wm2T[(size_t)(kb + kk + 1) * CE + t];
    float w2 = Wm2T[(size_t)(kb + kk + 2) * CE + t];
    float w3 = Wm2T[(size_t)(kb + kk + 3) * CE + t];
    #pragma unroll
    for (int r = 0; r < 32; ++r) {
      float4 hv = *(const float4*)&hl[r * 128 + kk];
      acc[r] += hv.x * w0 + hv.y * w1 + hv.z * w2 + hv.w * w3;
    }
  }
  #pragma unroll
  for (int r = 0; r < 32; ++r)
    part[((size_t)(rb + r) * 8 + kq) * CE + t] = acc[r];
}

// model_loss = (sum(partials)+bm2 - emb)^2
__global__ void ml_kernel(const float* __restrict__ part, const float* __restrict__ bm2,
                          const float* __restrict__ emb, float* __restrict__ ML) {
  int idx = blockIdx.x * 256 + threadIdx.x;   // < 2048*256
  int b = idx >> 8, e = idx & 255;
  float outv = bm2[e];
  #pragma unroll
  for (int q = 0; q < 8; ++q) outv += part[((size_t)b * 8 + q) * CE + e];
  float d = outv - emb[idx];
  ML[idx] = d * d;
}

// ---------------------------------------------------------------------------
// Device-wide barrier: monotonic counter, device-scope atomics + fences.
// All 256 blocks call it the same number of times.
// ---------------------------------------------------------------------------
__device__ __forceinline__ void gbar(int* bar, int* lgen) {
  __syncthreads();
  if (threadIdx.x == 0) {
    __threadfence();
    int target = 256 * (++(*lgen));
    __hip_atomic_fetch_add(bar, 1, __ATOMIC_ACQ_REL, __HIP_MEMORY_SCOPE_AGENT);
    while (__hip_atomic_load(bar, __ATOMIC_ACQUIRE, __HIP_MEMORY_SCOPE_AGENT) < target)
      __builtin_amdgcn_s_sleep(1);
    __threadfence();
  }
  __syncthreads();
}

// ---------------------------------------------------------------------------
// fin phase (runs on blocks 0..63, n = bid): epilogue of step s-1 + decision
// of step s. s==32: epilogue only. Ported verbatim from the verified kernel.
// ---------------------------------------------------------------------------
__device__ __forceinline__ void fin_phase(
    int s, int n, int t,
    const int* P, const float* Wsg, const float* bsg, const float* Wcg,
    const float* bcg, const float* bm2,
    const float* part, float* Xout, float* SLout, float* VALout, float* PAout,
    float* logits, int* Ibuf, int* Iupbuf, int* pushbuf, float* xsbuf,
    int* cnt, int* lists,
    float* sx, float* sred, float* svals, float* sxtra, int* sint) {
  if (s > 0) {
    int push = pushbuf[n];
    int I = Ibuf[n], Iup = Iupbuf[n];
    if (push) {
      float outv = bm2[t];
      #pragma unroll
      for (int q = 0; q < 8; ++q) outv += part[((size_t)n * 8 + q) * CE + t];
      Xout[((size_t)(n * CHP) + Iup) * CE + t] = outv;
      sx[t] = outv;
      if (t == 0) sint[1] = Iup;
    } else {
      int Inew = (I - 1 > 0) ? I - 1 : 0;
      sx[t] = Xout[((size_t)(n * CHP) + Inew) * CE + t];
      if (t == 0) sint[1] = Inew;
    }
    if (s == CS) return;  // final epilogue only
  } else {
    sx[t] = Xout[(size_t)(n * CHP) * CE + t];
    if (t == 0) sint[1] = 0;
  }
  __syncthreads();
  int I = sint[1];
  if (t == 0) Ibuf[n] = I;
  float xv = sx[t];
  float xa = fmaxf(xv, 0.f);
  xsbuf[n * 512 + t] = xa;
  xsbuf[n * 512 + 256 + t] = fmaxf(-xv, 0.f);
  sred[t] = xa * Wsg[t];
  __syncthreads();
  #pragma unroll
  for (int off = 128; off > 0; off >>= 1) {
    if (t < off) sred[t] += sred[t + off];
    __syncthreads();
  }
  if (t == 0) { sxtra[0] = sred[0] + bsg[0]; sint[0] = 1; }
  int c2 = t >> 3, g = t & 7;
  float pv = 0.f;
  #pragma unroll 4
  for (int i = 0; i < 32; ++i) {
    int e = g * 32 + i;
    pv += fmaxf(sx[e], 0.f) * Wcg[c2 * CE + e];
  }
  pv += __shfl_down(pv, 4, 8);
  pv += __shfl_down(pv, 2, 8);
  pv += __shfl_down(pv, 1, 8);
  if (g == 0) svals[c2] = pv + bcg[c2];
  __syncthreads();
  if (t < CA && logits[n * CA + t] != 0.f) sint[0] = 0;
  __syncthreads();
  int a = P[s * CN + n];
  if (t < CA) {
    float v = svals[t];
    float slv = sint[0] ? sxtra[0] * v : logits[n * CA + t];
    SLout[(size_t)(s * CN + n) * CA + t] = slv;
    logits[n * CA + t] = slv - (t == a ? 1e8f : 0.f);
    if (t == a) {
      VALout[s * CN + n] = slv;
      int pn = (v > 0.f) ? 1 : 0;
      pushbuf[n] = pn;
      PAout[n * CHP + I] = (float)a;
      Iupbuf[n] = (I + 1 < CHP - 1) ? I + 1 : CHP - 1;
      if (pn) {
        int slot = atomicAdd(&cnt[s * CA + a], 1);
        lists[(s * CA + a) * CN + slot] = n;
      }
    }
  }
  __syncthreads();
}

// ---------------------------------------------------------------------------
// Persistent planning kernel: 256 blocks (1/CU, forced by 139 KB LDS).
// Block (o,jt) holds Wpm[o][:, jt*128..+128) in 256 VGPRs/thread and the
// matching Wm2T j-slice in LDS. 2 device barriers per step, 64 total.
// ---------------------------------------------------------------------------
__global__ __launch_bounds__(256, 1) void plan_kernel(
    const float* __restrict__ Wpm, const float* __restrict__ Wm2T,
    const float* __restrict__ bm1g, const int* __restrict__ P,
    const float* Wsg, const float* bsg, const float* Wcg, const float* bcg,
    const float* bm2, float* Xout, float* SLout, float* VALout, float* PAout,
    float* logits, int* Ibuf, int* Iupbuf, int* pushbuf, float* xsbuf,
    int* cnt, int* lists, float* part, int* bar) {
  extern __shared__ float smem[];
  float* wm2s  = smem;                 // [256 e][130 pad-stride j] = 33280
  float* bm1s  = wm2s + 33280;         // 128
  float* red   = bm1s + 128;           // 8*128
  float* sh    = red + 1024;           // 128
  float* sxs   = sh + 128;             // 512
  float* sx    = sxs + 512;            // 256
  float* sred  = sx + 256;             // 256
  float* svals = sred + 256;           // 32
  float* sxtra = svals + 32;           // 2
  int*   sint  = (int*)(sxtra + 2);    // 2

  int bid = blockIdx.x, t = threadIdx.x;
  int o = bid >> 3, jt = bid & 7;
  int jl = t & 31, kq = t >> 5;
  int jb = jt * 128;

  // --- prologue: weights resident ---
  float4 wreg[64];
  {
    const float* wsrc = Wpm + ((size_t)o * 512 + (size_t)kq * 64) * CHID + jb + jl * 4;
    #pragma unroll
    for (int kk = 0; kk < 64; ++kk)
      wreg[kk] = *(const float4*)(wsrc + (size_t)kk * CHID);
  }
  for (int idx = t; idx < 128 * 256; idx += 256) {
    int e = idx & 255, j = idx >> 8;
    wm2s[e * 130 + j] = Wm2T[(size_t)(jb + j) * CE + e];
  }
  if (t < 128) bm1s[t] = bm1g[jb + t];
  __syncthreads();

  int lgen = 0;
  if (bid < CN)
    fin_phase(0, bid, t, P, Wsg, bsg, Wcg, bcg, bm2, part, Xout, SLout, VALout,
              PAout, logits, Ibuf, Iupbuf, pushbuf, xsbuf, cnt, lists,
              sx, sred, svals, sxtra, sint);
  gbar(bar, &lgen);

  for (int s = 0; s < CS; ++s) {
    // --- phase A: l1 + l2 partials for this option's pushed rows ---
    int c = cnt[s * CA + o];
    for (int r = 0; r < c; ++r) {
      int row = lists[(s * CA + o) * CN + r];
      for (int idx = t; idx < 512; idx += 256) sxs[idx] = xsbuf[row * 512 + idx];
      __syncthreads();
      float4 acc; acc.x = acc.y = acc.z = acc.w = 0.f;
      const float* xk = sxs + kq * 64;
      #pragma unroll
      for (int kk = 0; kk < 64; ++kk) {
        float xv = xk[kk];
        acc.x = fmaf(xv, wreg[kk].x, acc.x);
        acc.y = fmaf(xv, wreg[kk].y, acc.y);
        acc.z = fmaf(xv, wreg[kk].z, acc.z);
        acc.w = fmaf(xv, wreg[kk].w, acc.w);
      }
      *(float4*)&red[kq * 128 + jl * 4] = acc;
      __syncthreads();
      if (t < 128) {
        float s1 = 0.f;
        #pragma unroll
        for (int q = 0; q < 8; ++q) s1 += red[q * 128 + t];
        sh[t] = fmaxf(s1 + bm1s[t], 0.f);
      }
      __syncthreads();
      float a2 = 0.f;
      #pragma unroll 16
      for (int jj = 0; jj < 64; ++jj) {
        float2 hv = *(const float2*)&sh[jj * 2];
        float2 wv = *(const float2*)&wm2s[t * 130 + jj * 2];
        a2 = fmaf(hv.x, wv.x, fmaf(hv.y, wv.y, a2));
      }
      part[((size_t)row * 8 + jt) * CE + t] = a2;
      __syncthreads();
    }
    gbar(bar, &lgen);
    // --- fin: epilogue(s) + decision(s+1) ---
    if (bid < CN)
      fin_phase(s + 1, bid, t, P, Wsg, bsg, Wcg, bcg, bm2, part, Xout, SLout,
                VALout, PAout, logits, Ibuf, Iupbuf, pushbuf, xsbuf, cnt, lists,
                sx, sred, svals, sxtra, sint);
    if (s < CS - 1) gbar(bar, &lgen);
  }
}

// ---------------------------------------------------------------------------
// embed_loss
// ---------------------------------------------------------------------------
__global__ void el_kernel(const float* __restrict__ emb, const float* __restrict__ Xout,
                          const float* __restrict__ Ws, const float* __restrict__ bsp,
                          float* __restrict__ EL) {
  int tn = blockIdx.x;
  int n = tn & 63;
  int t = threadIdx.x, h = t >> 5, l = t & 31;
  const float* er = emb + (size_t)tn * CE;
  const float* xr = Xout + ((size_t)(n * CHP) + h) * CE;
  float pd = 0.f, px = 0.f, pe = 0.f, ps = 0.f;
  #pragma unroll
  for (int i = 0; i < 8; ++i) {
    int e = l * 8 + i;
    float ev = er[e], xv2 = xr[e];
    pd += ev * xv2; px += xv2 * xv2; pe += ev * ev; ps += fmaxf(ev, 0.f) * Ws[e];
  }
  #pragma unroll
  for (int off = 16; off > 0; off >>= 1) {
    pd += __shfl_down(pd, off, 32);
    px += __shfl_down(px, off, 32);
    pe += __shfl_down(pe, off, 32);
    ps += __shfl_down(ps, off, 32);
  }
  __shared__ float sdot[8], snx[8];
  __shared__ float sne, ssh;
  if (l == 0) {
    sdot[h] = pd;
    snx[h] = sqrtf(px);
    if (h == 0) { sne = sqrtf(pe); ssh = ps + bsp[0]; }
  }
  __syncthreads();
  if (t == 0) {
    const float eps = 1e-8f;
    float y[8];
    float m = -1e30f;
    #pragma unroll
    for (int hh = 0; hh < 8; ++hh) {
      float cs = sdot[hh] / ((sne + eps) * (snx[hh] + eps));
      y[hh] = ssh * cs;
      m = fmaxf(m, y[hh]);
    }
    float sum = 0.f;
    #pragma unroll
    for (int hh = 0; hh < 8; ++hh) sum += expf(y[hh] - m);
    float lse = logf(sum);
    float el = 0.f;
    #pragma unroll
    for (int hh = 0; hh < 8; ++hh) {
      float lp = y[hh] - m - lse;
      el += expf(lp) * lp;
    }
    EL[tn] = el;
  }
}

// ---------------------------------------------------------------------------
extern "C" void kernel_launch(void* const* d_in, const int* in_sizes, int n_in,
                              void* d_out, int out_size, void* d_ws, size_t ws_size,
                              hipStream_t stream) {
  (void)in_sizes; (void)n_in; (void)out_size; (void)ws_size;
  const int*   obs    = (const int*)d_in[0];
  const int*   P      = (const int*)d_in[1];
  const float* embed1 = (const float*)d_in[2];
  const float* Wih    = (const float*)d_in[3];
  // d_in[4] = Whh: provably unused (h0 = 0 and only Hs[0] is consumed)
  const float* bih    = (const float*)d_in[5];
  const float* bhh    = (const float*)d_in[6];
  const float* We2    = (const float*)d_in[7];
  const float* be2    = (const float*)d_in[8];
  const float* Ws     = (const float*)d_in[9];
  const float* bs     = (const float*)d_in[10];
  const float* Wc     = (const float*)d_in[11];
  const float* bc     = (const float*)d_in[12];
  const float* Wm1    = (const float*)d_in[13];
  const float* bm1    = (const float*)d_in[14];
  const float* Wm2    = (const float*)d_in[15];
  const float* bm2    = (const float*)d_in[16];
  const float* eo     = (const float*)d_in[17];
  float* out = (float*)d_out;
  char*  ws  = (char*)d_ws;

  float* emb    = (float*)(ws + B_EMB);
  float* h1     = (float*)(ws + B_H1);
  float* xsp    = (float*)(ws + B_XS);
  float* part   = (float*)(ws + B_PART);
  float* logits = (float*)(ws + B_LOG);
  int*   Ibuf   = (int*)(ws + B_IBUF);
  int*   Iup    = (int*)(ws + B_IUP);
  int*   push   = (int*)(ws + B_PUSH);
  int*   bar    = (int*)(ws + B_BAR);
  int*   cntp   = (int*)(ws + B_CNT);
  int*   listp  = (int*)(ws + B_LISTS);
  int*   cnttl  = (int*)(ws + B_CNTTL);
  int*   listtl = (int*)(ws + B_LISTTL);
  float* we2t   = (float*)(ws + B_WE2T);
  float* wm1t   = (float*)(ws + B_WM1T);
  float* xstl   = (float*)(ws + B_XSTL);
  float* hbig   = (float*)(ws + B_HBIG);
  float* parttl = (float*)(ws + B_PARTTL);
  float* wm2t   = (float*)(ws + B_WM2T);
  float* wpm    = (float*)(ws + B_WPM);

  dim3 thr(256);
  init_kernel<<<dim3(514), thr, 0, stream>>>(out, logits, cntp, cnttl, bar);
  emb_kernel<<<dim3(256), thr, 0, stream>>>(obs, embed1, emb);
  h1_kernel<<<dim3(256), thr, 0, stream>>>(emb, Wih, bih, bhh, h1);
  trans_kernel<<<dim3(16, 4), thr, 0, stream>>>(We2, we2t, CE, CHID);        // We2T
  x0_kernel<<<dim3(4, 64), thr, 0, stream>>>(h1, we2t, be2, out + O_X);
  trans_kernel<<<dim3(128, 16), thr, 0, stream>>>(Wm1, wm1t, CHID, CA * CE); // Wm1T
  wpm_kernel<<<dim3(256, 4), thr, 0, stream>>>(wm1t, eo, wpm);
  trans_kernel<<<dim3(16, 4), thr, 0, stream>>>(Wm2, wm2t, CE, CHID);        // Wm2T
  tllists_kernel<<<dim3(8), thr, 0, stream>>>(P, cnttl, listtl);
  xstl_kernel<<<dim3(4096), thr, 0, stream>>>(emb, xstl);
  // time-loop model (factorized, f32)
  l1_kernel<<<dim3(32, 8, 8), thr, 0, stream>>>(wpm, xstl, bm1, cnttl, listtl, 256, hbig);
  l2big_kernel<<<dim3(8, 64), thr, 0, stream>>>(hbig, wm2t, parttl);
  ml_kernel<<<dim3(2048), thr, 0, stream>>>(parttl, bm2, emb, out + O_ML);
  // planning loop: single persistent kernel, device barriers inside
  constexpr size_t PLAN_SMEM = 35624 * sizeof(float);  // ~139 KB
  plan_kernel<<<dim3(256), thr, PLAN_SMEM, stream>>>(
      wpm, wm2t, bm1, P, Ws, bs, Wc, bc, bm2,
      out + O_X, out + O_SL, out + O_VAL, out + O_PA,
      logits, Ibuf, Iup, push, xsp, cntp, listp, part, bar);
  el_kernel<<<dim3(2048), thr, 0, stream>>>(emb, out + O_X, Ws, bs, out + O_EL);
}

// Round 3
// 1194.496 us; speedup vs baseline: 2.4250x; 2.4250x over previous
//
#include <hip/hip_runtime.h>

// ---------------------------------------------------------------------------
// Problem constants
// ---------------------------------------------------------------------------
constexpr int CT = 32;      // T
constexpr int CN = 64;      // N
constexpr int CE = 256;     // E = DOBS*V
constexpr int CHID = 1024;
constexpr int CA = 32;      // num options
constexpr int CS = 32;      // planning steps
constexpr int CHP = 8;      // planning horizon
constexpr int TN = CT * CN; // 2048

// d_out float offsets (return order: search_logits, planned_actions, X, value,
// model_loss, embed_loss)
constexpr size_t O_SL  = 0;        // 32*64*32 = 65536
constexpr size_t O_PA  = 65536;    // 64*8     = 512
constexpr size_t O_X   = 66048;    // 64*8*256 = 131072
constexpr size_t O_VAL = 197120;   // 32*64    = 2048
constexpr size_t O_ML  = 199168;   // 32*64*256= 524288
constexpr size_t O_EL  = 723456;   // 32*64    = 2048

// ws byte offsets (~100 MB total)
constexpr size_t B_EMB    = 0;                           // 2 MB   [2048][256] f32
constexpr size_t B_H1     = 2u * 1024 * 1024;            // 256 KB [64][1024]
constexpr size_t B_XS     = B_H1 + 256 * 1024;           // 128 KB [64][512]
constexpr size_t B_PART   = B_XS + 128 * 1024;           // 512 KB [64][8][256]
constexpr size_t B_LOG    = 3u * 1024 * 1024;            // 8 KB   [64][32]
constexpr size_t B_IBUF   = B_LOG + 8 * 1024;
constexpr size_t B_IUP    = B_IBUF + 1024;
constexpr size_t B_PUSH   = B_IUP + 1024;
constexpr size_t B_BAR    = B_PUSH + 1024;
constexpr size_t B_CNT    = B_LOG + 16 * 1024;           // 33*32 ints
constexpr size_t B_LISTS  = B_LOG + 32 * 1024;           // 32*32*64 ints = 256 KB
constexpr size_t B_CNTTL  = B_LOG + 384 * 1024;          // 32 ints
constexpr size_t B_LISTTL = B_CNTTL + 1024;              // 32 KB [32][256]
// 32MB+ multi-phase region: We2T (early) -> Wm1T (mid) -> xstl/hbig/parttl/Wm2T
constexpr size_t B_R32    = 4u * 1024 * 1024;
constexpr size_t B_WE2T   = B_R32;                       // 1 MB  (dead after x0)
constexpr size_t B_WM1T   = B_R32;                       // 32 MB (dead after wpm)
constexpr size_t B_XSTL   = B_R32;                       // 4 MB  [2048][512]
constexpr size_t B_HBIG   = B_R32 + 4u * 1024 * 1024;    // 8 MB  [2048][1024]
constexpr size_t B_PARTTL = B_R32 + 12u * 1024 * 1024;   // 16 MB [2048][8][256]
constexpr size_t B_WM2T   = B_R32 + 28u * 1024 * 1024;   // 1 MB  [1024][256]
constexpr size_t B_WPM    = B_R32 + 32u * 1024 * 1024;   // 64 MB [32][512][1024]

__device__ __forceinline__ void fma4(float4& a, float s, const float4& w) {
  a.x = fmaf(s, w.x, a.x); a.y = fmaf(s, w.y, a.y);
  a.z = fmaf(s, w.z, a.z); a.w = fmaf(s, w.w, a.w);
}

// ---------------------------------------------------------------------------
// init: zero PA+X span of d_out, logits, per-step cnt, tl cnt, barrier
// ---------------------------------------------------------------------------
__global__ void init_kernel(float* __restrict__ out, float* __restrict__ logits,
                            int* __restrict__ cnt, int* __restrict__ cnt_tl,
                            int* __restrict__ bar) {
  int idx = blockIdx.x * 256 + threadIdx.x;
  if (idx < 131584) out[O_PA + idx] = 0.f;  // PA (512) + X (131072) contiguous
  if (idx < CN * CA) logits[idx] = 0.f;
  if (idx < 33 * CA) cnt[idx] = 0;
  if (idx < CA) cnt_tl[idx] = 0;
  if (idx < 2) bar[idx] = 0;
}

// ---------------------------------------------------------------------------
// emb[t][n][e] = embed1[obs[t][n][e>>4]][e&15]
// ---------------------------------------------------------------------------
__global__ void emb_kernel(const int* __restrict__ obs, const float* __restrict__ embed1,
                           float* __restrict__ emb) {
  int idx = blockIdx.x * 256 + threadIdx.x;
  int b = idx >> 5, k8 = idx & 31;
  int e0 = k8 * 8;
  int d = e0 >> 4;
  int o = obs[b * 16 + d];
  const float* src = embed1 + o * 16 + (e0 & 15);
  float4 v0 = *(const float4*)src;
  float4 v1 = *(const float4*)(src + 4);
  float* dst = emb + (size_t)b * CE + e0;
  *(float4*)dst = v0;
  *(float4*)(dst + 4) = v1;
}

// ---------------------------------------------------------------------------
// One GRU step with h0 = 0 (only Hs[0] used downstream; Whh provably unused)
// ---------------------------------------------------------------------------
__global__ void h1_kernel(const float* __restrict__ emb, const float* __restrict__ Wih,
                          const float* __restrict__ bih, const float* __restrict__ bhh,
                          float* __restrict__ h1) {
  int t = threadIdx.x, bid = blockIdx.x;   // 256 blocks of (64n x 4j)
  int n = t & 63, j = bid * 4 + (t >> 6);
  const float* x = emb + (size_t)n * CE;   // emb[0] rows
  const float* wr = Wih + (size_t)j * CE;
  const float* wz = Wih + (size_t)(CHID + j) * CE;
  const float* wn = Wih + (size_t)(2 * CHID + j) * CE;
  float ar = 0.f, az = 0.f, an = 0.f;
  #pragma unroll 4
  for (int e = 0; e < CE; ++e) {
    float xe = x[e];
    ar += xe * wr[e]; az += xe * wz[e]; an += xe * wn[e];
  }
  ar += bih[j] + bhh[j];
  az += bih[CHID + j] + bhh[CHID + j];
  float r = 1.f / (1.f + expf(-ar));
  float z = 1.f / (1.f + expf(-az));
  float nn = tanhf(an + bih[2 * CHID + j] + r * bhh[2 * CHID + j]);
  h1[(size_t)n * CHID + j] = (1.f - z) * nn;
}

// ---------------------------------------------------------------------------
// Generic 64x64 tiled transpose: in[R][C] -> out[C][R]
// ---------------------------------------------------------------------------
__global__ void trans_kernel(const float* __restrict__ in, float* __restrict__ out,
                             int R, int C) {
  __shared__ float tile[64][65];
  int tj = threadIdx.x & 63, tg = threadIdx.x >> 6;
  int cb = blockIdx.x * 64, rb = blockIdx.y * 64;
  #pragma unroll
  for (int i = 0; i < 16; ++i) {
    int r = tg * 16 + i;
    tile[r][tj] = in[(size_t)(rb + r) * C + cb + tj];
  }
  __syncthreads();
  #pragma unroll
  for (int i = 0; i < 16; ++i) {
    int c2 = tg * 16 + i;
    out[(size_t)(cb + c2) * R + rb + tj] = tile[tj][c2];
  }
}

// ---------------------------------------------------------------------------
// X[:,0] = h1 @ We2^T + be2   (We2T layout [k][e])
// ---------------------------------------------------------------------------
__global__ void x0_kernel(const float* __restrict__ h1, const float* __restrict__ We2T,
                          const float* __restrict__ be2, float* __restrict__ Xout) {
  int et = blockIdx.x, n = blockIdx.y, t = threadIdx.x;
  int el = t & 63, kq = t >> 6;
  __shared__ float hr[1024];
  __shared__ float sred2[4][64];
  for (int idx = t; idx < 1024; idx += 256) hr[idx] = h1[(size_t)n * CHID + idx];
  __syncthreads();
  int e = et * 64 + el;
  float acc = 0.f;
  for (int k = kq * 256; k < kq * 256 + 256; ++k) acc += hr[k] * We2T[(size_t)k * CE + e];
  sred2[kq][el] = acc;
  __syncthreads();
  if (t < 64) {
    float s2 = sred2[0][t] + sred2[1][t] + sred2[2][t] + sred2[3][t] + be2[et * 64 + t];
    Xout[(size_t)(n * CHP) * CE + et * 64 + t] = s2;
  }
}

// ---------------------------------------------------------------------------
// Factorized model weights:
// Wpm[o][e][j]     = sum_a relu( embed_opt[o][a]) * Wm1[j][a*256+e]
// Wpm[o][256+e][j] = sum_a relu(-embed_opt[o][a]) * Wm1[j][a*256+e]
// ---------------------------------------------------------------------------
__global__ void wpm_kernel(const float* __restrict__ Wm1T, const float* __restrict__ eo,
                           float* __restrict__ Wpm) {
  int e = blockIdx.x, jt = blockIdx.y, t = threadIdx.x;
  int j = jt * 256 + t;
  __shared__ float rp[CA * CA], rm[CA * CA];
  for (int idx = t; idx < CA * CA; idx += 256) {
    float v = eo[idx];
    rp[idx] = fmaxf(v, 0.f);
    rm[idx] = fmaxf(-v, 0.f);
  }
  __syncthreads();
  float w[32];
  #pragma unroll
  for (int a = 0; a < 32; ++a) w[a] = Wm1T[(size_t)(a * 256 + e) * CHID + j];
  for (int o = 0; o < 32; ++o) {
    float sp = 0.f, sm = 0.f;
    #pragma unroll
    for (int a = 0; a < 32; ++a) {
      float wa = w[a];
      sp += rp[o * 32 + a] * wa;
      sm += rm[o * 32 + a] * wa;
    }
    Wpm[((size_t)o * 512 + e) * CHID + j] = sp;
    Wpm[((size_t)o * 512 + 256 + e) * CHID + j] = sm;
  }
}

// ---------------------------------------------------------------------------
// Group time-loop rows by option (list order nondeterministic; results aren't)
// ---------------------------------------------------------------------------
__global__ void tllists_kernel(const int* __restrict__ P, int* __restrict__ cnt_tl,
                               int* __restrict__ list_tl) {
  int b = blockIdx.x * 256 + threadIdx.x;
  if (b >= TN) return;
  int a = P[b];
  int slot = atomicAdd(&cnt_tl[a], 1);
  list_tl[a * 256 + slot] = b;
}

// xs_tl[b][k] = relu(+/- prev[b][k&255]),  prev = emb shifted by one t (wrap)
__global__ void xstl_kernel(const float* __restrict__ emb, float* __restrict__ xs) {
  int idx = blockIdx.x * 256 + threadIdx.x;   // < 2048*512
  int b = idx >> 9, k = idx & 511;
  int e = k & 255;
  int bp = (b < CN) ? (b + (CT - 1) * CN) : (b - CN);
  float v = emb[(size_t)bp * CE + e];
  xs[idx] = (k < 256) ? fmaxf(v, 0.f) : fmaxf(-v, 0.f);
}

// ---------------------------------------------------------------------------
// Time-loop factorized model layer 1:
// h[row][j] = relu( sum_{k<512} xs[row][k] * Wpm[o][k][j] + bm1[j] )
// grid (32 o, 8 j-tiles of 128, z row-group start)
// ---------------------------------------------------------------------------
__global__ __launch_bounds__(256) void l1_kernel(
    const float* __restrict__ Wpm, const float* __restrict__ xs,
    const float* __restrict__ bm1, const int* __restrict__ cnt,
    const int* __restrict__ list, int listStride, float* __restrict__ hout) {
  int o = blockIdx.x, jt = blockIdx.y;
  int c = cnt[o];
  if (c <= 0) return;
  __shared__ __align__(16) float sbuf[8192];
  __shared__ int srows[8];
  int t = threadIdx.x;
  int jl = t & 31, kq = t >> 5;
  int jb = jt * 128;
  const float* wb = Wpm + (size_t)o * (512 * CHID) + jb + jl * 4;
  for (int g = blockIdx.z; g * 8 < c; g += gridDim.z) {
    int base = g * 8;
    int nr = min(8, c - base);
    if (t < 8) srows[t] = (t < nr) ? list[o * listStride + base + t] : -1;
    __syncthreads();
    for (int idx = t; idx < 4096; idx += 256) {
      int row = srows[idx >> 9];
      sbuf[idx] = (row >= 0) ? xs[(size_t)row * 512 + (idx & 511)] : 0.f;
    }
    __syncthreads();
    float4 acc[8];
    #pragma unroll
    for (int r = 0; r < 8; ++r) acc[r] = make_float4(0.f, 0.f, 0.f, 0.f);
    int kbase = kq * 64;
    for (int k4 = 0; k4 < 64; k4 += 4) {
      int k = kbase + k4;
      float4 w0 = *(const float4*)(wb + (size_t)(k + 0) * CHID);
      float4 w1 = *(const float4*)(wb + (size_t)(k + 1) * CHID);
      float4 w2 = *(const float4*)(wb + (size_t)(k + 2) * CHID);
      float4 w3 = *(const float4*)(wb + (size_t)(k + 3) * CHID);
      #pragma unroll
      for (int r = 0; r < 8; ++r) {
        float4 xv = *(const float4*)&sbuf[r * 512 + k];
        fma4(acc[r], xv.x, w0); fma4(acc[r], xv.y, w1);
        fma4(acc[r], xv.z, w2); fma4(acc[r], xv.w, w3);
      }
    }
    __syncthreads();
    #pragma unroll
    for (int r = 0; r < 8; ++r)
      *(float4*)&sbuf[(kq * 8 + r) * 128 + jl * 4] = acc[r];
    __syncthreads();
    for (int idx = t; idx < 1024; idx += 256) {
      int r = idx >> 7, jc = idx & 127;
      float s = 0.f;
      #pragma unroll
      for (int q = 0; q < 8; ++q) s += sbuf[(q * 8 + r) * 128 + jc];
      int row = srows[r];
      if (row >= 0)
        hout[(size_t)row * CHID + jb + jc] = fmaxf(s + bm1[jb + jc], 0.f);
    }
    __syncthreads();
  }
}

// ---------------------------------------------------------------------------
// Time-loop layer 2 partials: part[b][kq][e], 8 k-slices of 128
// grid (8 kq, 64 row-groups of 32), 256 thr (= e)
// ---------------------------------------------------------------------------
__global__ __launch_bounds__(256) void l2big_kernel(const float* __restrict__ h,
    const float* __restrict__ Wm2T, float* __restrict__ part) {
  int kq = blockIdx.x, rg = blockIdx.y, t = threadIdx.x;
  int rb = rg * 32, kb = kq * 128;
  __shared__ __align__(16) float hl[4096];
  for (int idx = t; idx < 4096; idx += 256)
    hl[idx] = h[(size_t)(rb + (idx >> 7)) * CHID + kb + (idx & 127)];
  __syncthreads();
  float acc[32];
  #pragma unroll
  for (int r = 0; r < 32; ++r) acc[r] = 0.f;
  for (int kk = 0; kk < 128; kk += 4) {
    float w0 = Wm2T[(size_t)(kb + kk + 0) * CE + t];
    float w1 = Wm2T[(size_t)(kb + kk + 1) * CE + t];
    float w2 = Wm2T[(size_t)(kb + kk + 2) * CE + t];
    float w3 = Wm2T[(size_t)(kb + kk + 3) * CE + t];
    #pragma unroll
    for (int r = 0; r < 32; ++r) {
      float4 hv = *(const float4*)&hl[r * 128 + kk];
      acc[r] += hv.x * w0 + hv.y * w1 + hv.z * w2 + hv.w * w3;
    }
  }
  #pragma unroll
  for (int r = 0; r < 32; ++r)
    part[((size_t)(rb + r) * 8 + kq) * CE + t] = acc[r];
}

// model_loss = (sum(partials)+bm2 - emb)^2
__global__ void ml_kernel(const float* __restrict__ part, const float* __restrict__ bm2,
                          const float* __restrict__ emb, float* __restrict__ ML) {
  int idx = blockIdx.x * 256 + threadIdx.x;   // < 2048*256
  int b = idx >> 8, e = idx & 255;
  float outv = bm2[e];
  #pragma unroll
  for (int q = 0; q < 8; ++q) outv += part[((size_t)b * 8 + q) * CE + e];
  float d = outv - emb[idx];
  ML[idx] = d * d;
}

// ---------------------------------------------------------------------------
// Device-wide barrier (256 blocks, all call equally).
// Key fix vs round 2: spin with RELAXED cache-bypassing atomic loads (no L2
// invalidation per iteration); exactly ONE release fence before arrive and
// ONE acquire fence after exit.
// ---------------------------------------------------------------------------
__device__ __forceinline__ void gbar(int* bar, int* lgen) {
  __syncthreads();
  if (threadIdx.x == 0) {
    int target = 256 * (++(*lgen));
    __builtin_amdgcn_fence(__ATOMIC_RELEASE, "agent");      // writeback local L2
    __hip_atomic_fetch_add(bar, 1, __ATOMIC_RELAXED, __HIP_MEMORY_SCOPE_AGENT);
    while (__hip_atomic_load(bar, __ATOMIC_RELAXED, __HIP_MEMORY_SCOPE_AGENT) < target)
      __builtin_amdgcn_s_sleep(4);
    __builtin_amdgcn_fence(__ATOMIC_ACQUIRE, "agent");      // one L1/L2 invalidate
  }
  __syncthreads();
}

// ---------------------------------------------------------------------------
// fin phase, 512-thread variant (blocks 0..63, n = bid). All __syncthreads
// unconditional; compute guarded to t<256. Logic identical to the verified
// round-1 fin_kernel. s==32: epilogue only.
// ---------------------------------------------------------------------------
__device__ __forceinline__ void fin_phase(
    int s, int n, int t,
    const int* P, const float* Wsg, const float* bsg, const float* Wcg,
    const float* bcg, const float* bm2,
    const float* part, float* Xout, float* SLout, float* VALout, float* PAout,
    float* logits, int* Ibuf, int* Iupbuf, int* pushbuf, float* xsbuf,
    int* cnt, int* lists,
    float* sx, float* sred, float* svals, float* sxtra, int* sint) {
  if (s > 0) {
    int push = pushbuf[n];
    int I = Ibuf[n], Iup = Iupbuf[n];
    if (push) {
      if (t < 256) {
        float outv = bm2[t];
        #pragma unroll
        for (int q = 0; q < 8; ++q) outv += part[((size_t)n * 8 + q) * CE + t];
        Xout[((size_t)(n * CHP) + Iup) * CE + t] = outv;
        sx[t] = outv;
      }
      if (t == 0) sint[1] = Iup;
    } else {
      int Inew = (I - 1 > 0) ? I - 1 : 0;
      if (t < 256) sx[t] = Xout[((size_t)(n * CHP) + Inew) * CE + t];
      if (t == 0) sint[1] = Inew;
    }
    if (s == CS) return;  // uniform per block: final epilogue only
  } else {
    if (t < 256) sx[t] = Xout[(size_t)(n * CHP) * CE + t];
    if (t == 0) sint[1] = 0;
  }
  __syncthreads();
  int I = sint[1];
  if (t == 0) Ibuf[n] = I;
  if (t < 256) {
    float xv = sx[t];
    float xa = fmaxf(xv, 0.f);
    xsbuf[n * 512 + t] = xa;
    xsbuf[n * 512 + 256 + t] = fmaxf(-xv, 0.f);
    sred[t] = xa * Wsg[t];
  }
  __syncthreads();
  #pragma unroll
  for (int off = 128; off > 0; off >>= 1) {
    if (t < off) sred[t] += sred[t + off];
    __syncthreads();
  }
  if (t == 0) { sxtra[0] = sred[0] + bsg[0]; sint[0] = 1; }
  if (t < 256) {
    int c2 = t >> 3, g = t & 7;
    float pv = 0.f;
    #pragma unroll 4
    for (int i = 0; i < 32; ++i) {
      int e = g * 32 + i;
      pv += fmaxf(sx[e], 0.f) * Wcg[c2 * CE + e];
    }
    pv += __shfl_down(pv, 4, 8);
    pv += __shfl_down(pv, 2, 8);
    pv += __shfl_down(pv, 1, 8);
    if (g == 0) svals[c2] = pv + bcg[c2];
  }
  __syncthreads();
  if (t < CA && logits[n * CA + t] != 0.f) sint[0] = 0;
  __syncthreads();
  int a = P[s * CN + n];
  if (t < CA) {
    float v = svals[t];
    float slv = sint[0] ? sxtra[0] * v : logits[n * CA + t];
    SLout[(size_t)(s * CN + n) * CA + t] = slv;
    logits[n * CA + t] = slv - (t == a ? 1e8f : 0.f);
    if (t == a) {
      VALout[s * CN + n] = slv;
      int pn = (v > 0.f) ? 1 : 0;
      pushbuf[n] = pn;
      PAout[n * CHP + I] = (float)a;
      Iupbuf[n] = (I + 1 < CHP - 1) ? I + 1 : CHP - 1;
      if (pn) {
        int slot = atomicAdd(&cnt[s * CA + a], 1);
        lists[(s * CA + a) * CN + slot] = n;
      }
    }
  }
  __syncthreads();
}

// ---------------------------------------------------------------------------
// Persistent planning kernel: 256 blocks x 512 threads (1 block/CU, LDS-forced).
// Block (o,jt): Wpm[o][:, jb..jb+128) in 128 VGPRs/thread (32 float4, spill-
// safe under __launch_bounds__(512,2) -> 256 VGPR cap) + Wm2T j-slice in LDS.
// 64 relaxed-spin device barriers total.
// ---------------------------------------------------------------------------
__global__ __launch_bounds__(512, 2) void plan_kernel(
    const float* __restrict__ Wpm, const float* __restrict__ Wm2T,
    const float* __restrict__ bm1g, const int* __restrict__ P,
    const float* Wsg, const float* bsg, const float* Wcg, const float* bcg,
    const float* bm2, float* Xout, float* SLout, float* VALout, float* PAout,
    float* logits, int* Ibuf, int* Iupbuf, int* pushbuf, float* xsbuf,
    int* cnt, int* lists, float* part, int* bar) {
  extern __shared__ float smem[];
  float* wm2s  = smem;                 // [256 e][130 pad] = 33280
  float* bm1s  = wm2s + 33280;         // 128
  float* red   = bm1s + 128;           // 16*128 = 2048
  float* sh    = red + 2048;           // 128
  float* sxs   = sh + 128;             // 8*512 = 4096
  float* sx    = sxs + 4096;           // 256
  float* sred  = sx + 256;             // 256
  float* svals = sred + 256;           // 32
  float* sxtra = svals + 32;           // 2
  int*   sint  = (int*)(sxtra + 2);    // 2
  int*   srows = sint + 2;             // 8
  // total 40236 slots = 160944 B (<= 160 KiB)

  int bid = blockIdx.x, t = threadIdx.x;
  int o = bid >> 3, jt = bid & 7;
  int jl = t & 31, kq = t >> 5;        // kq in [0,16): 32 k each
  int jb = jt * 128;

  // --- prologue: weights resident ---
  float4 wreg[32];
  {
    const float* wsrc = Wpm + ((size_t)o * 512 + (size_t)kq * 32) * CHID + jb + jl * 4;
    #pragma unroll
    for (int kk = 0; kk < 32; ++kk)
      wreg[kk] = *(const float4*)(wsrc + (size_t)kk * CHID);
  }
  for (int idx = t; idx < 128 * 256; idx += 512) {
    int e = idx & 255, j = idx >> 8;
    wm2s[e * 130 + j] = Wm2T[(size_t)(jb + j) * CE + e];
  }
  if (t < 128) bm1s[t] = bm1g[jb + t];
  __syncthreads();

  int lgen = 0;
  if (bid < CN)
    fin_phase(0, bid, t, P, Wsg, bsg, Wcg, bcg, bm2, part, Xout, SLout, VALout,
              PAout, logits, Ibuf, Iupbuf, pushbuf, xsbuf, cnt, lists,
              sx, sred, svals, sxtra, sint);
  gbar(bar, &lgen);

  for (int s = 0; s < CS; ++s) {
    // --- phase A: l1+l2 partials for this option's pushed rows (batches of 8)
    int c = cnt[s * CA + o];
    for (int base = 0; base < c; base += 8) {
      int nb2 = min(8, c - base);
      if (t < 8) srows[t] = (t < nb2) ? lists[(s * CA + o) * CN + base + t] : -1;
      __syncthreads();
      for (int idx = t; idx < 4096; idx += 512) {
        int row = srows[idx >> 9];
        sxs[idx] = (row >= 0) ? xsbuf[row * 512 + (idx & 511)] : 0.f;
      }
      __syncthreads();
      for (int r = 0; r < nb2; ++r) {
        float4 acc; acc.x = acc.y = acc.z = acc.w = 0.f;
        const float* xk = sxs + r * 512 + kq * 32;
        #pragma unroll
        for (int kk = 0; kk < 32; ++kk) {
          float xv = xk[kk];
          acc.x = fmaf(xv, wreg[kk].x, acc.x);
          acc.y = fmaf(xv, wreg[kk].y, acc.y);
          acc.z = fmaf(xv, wreg[kk].z, acc.z);
          acc.w = fmaf(xv, wreg[kk].w, acc.w);
        }
        *(float4*)&red[kq * 128 + jl * 4] = acc;
        __syncthreads();
        if (t < 128) {
          float s1 = 0.f;
          #pragma unroll
          for (int q = 0; q < 16; ++q) s1 += red[q * 128 + t];
          sh[t] = fmaxf(s1 + bm1s[t], 0.f);
        }
        __syncthreads();
        if (t < 256) {
          float a2 = 0.f;
          #pragma unroll 16
          for (int jj = 0; jj < 64; ++jj) {
            float2 hv = *(const float2*)&sh[jj * 2];
            float2 wv = *(const float2*)&wm2s[t * 130 + jj * 2];
            a2 = fmaf(hv.x, wv.x, fmaf(hv.y, wv.y, a2));
          }
          part[((size_t)srows[r] * 8 + jt) * CE + t] = a2;
        }
        __syncthreads();
      }
    }
    gbar(bar, &lgen);
    // --- fin: epilogue(s) + decision(s+1) ---
    if (bid < CN)
      fin_phase(s + 1, bid, t, P, Wsg, bsg, Wcg, bcg, bm2, part, Xout, SLout,
                VALout, PAout, logits, Ibuf, Iupbuf, pushbuf, xsbuf, cnt, lists,
                sx, sred, svals, sxtra, sint);
    if (s < CS - 1) gbar(bar, &lgen);
  }
}

// ---------------------------------------------------------------------------
// embed_loss
// ---------------------------------------------------------------------------
__global__ void el_kernel(const float* __restrict__ emb, const float* __restrict__ Xout,
                          const float* __restrict__ Ws, const float* __restrict__ bsp,
                          float* __restrict__ EL) {
  int tn = blockIdx.x;
  int n = tn & 63;
  int t = threadIdx.x, h = t >> 5, l = t & 31;
  const float* er = emb + (size_t)tn * CE;
  const float* xr = Xout + ((size_t)(n * CHP) + h) * CE;
  float pd = 0.f, px = 0.f, pe = 0.f, ps = 0.f;
  #pragma unroll
  for (int i = 0; i < 8; ++i) {
    int e = l * 8 + i;
    float ev = er[e], xv2 = xr[e];
    pd += ev * xv2; px += xv2 * xv2; pe += ev * ev; ps += fmaxf(ev, 0.f) * Ws[e];
  }
  #pragma unroll
  for (int off = 16; off > 0; off >>= 1) {
    pd += __shfl_down(pd, off, 32);
    px += __shfl_down(px, off, 32);
    pe += __shfl_down(pe, off, 32);
    ps += __shfl_down(ps, off, 32);
  }
  __shared__ float sdot[8], snx[8];
  __shared__ float sne, ssh;
  if (l == 0) {
    sdot[h] = pd;
    snx[h] = sqrtf(px);
    if (h == 0) { sne = sqrtf(pe); ssh = ps + bsp[0]; }
  }
  __syncthreads();
  if (t == 0) {
    const float eps = 1e-8f;
    float y[8];
    float m = -1e30f;
    #pragma unroll
    for (int hh = 0; hh < 8; ++hh) {
      float cs = sdot[hh] / ((sne + eps) * (snx[hh] + eps));
      y[hh] = ssh * cs;
      m = fmaxf(m, y[hh]);
    }
    float sum = 0.f;
    #pragma unroll
    for (int hh = 0; hh < 8; ++hh) sum += expf(y[hh] - m);
    float lse = logf(sum);
    float el = 0.f;
    #pragma unroll
    for (int hh = 0; hh < 8; ++hh) {
      float lp = y[hh] - m - lse;
      el += expf(lp) * lp;
    }
    EL[tn] = el;
  }
}

// ---------------------------------------------------------------------------
extern "C" void kernel_launch(void* const* d_in, const int* in_sizes, int n_in,
                              void* d_out, int out_size, void* d_ws, size_t ws_size,
                              hipStream_t stream) {
  (void)in_sizes; (void)n_in; (void)out_size; (void)ws_size;
  const int*   obs    = (const int*)d_in[0];
  const int*   P      = (const int*)d_in[1];
  const float* embed1 = (const float*)d_in[2];
  const float* Wih    = (const float*)d_in[3];
  // d_in[4] = Whh: provably unused (h0 = 0 and only Hs[0] is consumed)
  const float* bih    = (const float*)d_in[5];
  const float* bhh    = (const float*)d_in[6];
  const float* We2    = (const float*)d_in[7];
  const float* be2    = (const float*)d_in[8];
  const float* Ws     = (const float*)d_in[9];
  const float* bs     = (const float*)d_in[10];
  const float* Wc     = (const float*)d_in[11];
  const float* bc     = (const float*)d_in[12];
  const float* Wm1    = (const float*)d_in[13];
  const float* bm1    = (const float*)d_in[14];
  const float* Wm2    = (const float*)d_in[15];
  const float* bm2    = (const float*)d_in[16];
  const float* eo     = (const float*)d_in[17];
  float* out = (float*)d_out;
  char*  ws  = (char*)d_ws;

  float* emb    = (float*)(ws + B_EMB);
  float* h1     = (float*)(ws + B_H1);
  float* xsp    = (float*)(ws + B_XS);
  float* part   = (float*)(ws + B_PART);
  float* logits = (float*)(ws + B_LOG);
  int*   Ibuf   = (int*)(ws + B_IBUF);
  int*   Iup    = (int*)(ws + B_IUP);
  int*   push   = (int*)(ws + B_PUSH);
  int*   bar    = (int*)(ws + B_BAR);
  int*   cntp   = (int*)(ws + B_CNT);
  int*   listp  = (int*)(ws + B_LISTS);
  int*   cnttl  = (int*)(ws + B_CNTTL);
  int*   listtl = (int*)(ws + B_LISTTL);
  float* we2t   = (float*)(ws + B_WE2T);
  float* wm1t   = (float*)(ws + B_WM1T);
  float* xstl   = (float*)(ws + B_XSTL);
  float* hbig   = (float*)(ws + B_HBIG);
  float* parttl = (float*)(ws + B_PARTTL);
  float* wm2t   = (float*)(ws + B_WM2T);
  float* wpm    = (float*)(ws + B_WPM);

  dim3 thr(256);
  init_kernel<<<dim3(514), thr, 0, stream>>>(out, logits, cntp, cnttl, bar);
  emb_kernel<<<dim3(256), thr, 0, stream>>>(obs, embed1, emb);
  h1_kernel<<<dim3(256), thr, 0, stream>>>(emb, Wih, bih, bhh, h1);
  trans_kernel<<<dim3(16, 4), thr, 0, stream>>>(We2, we2t, CE, CHID);        // We2T
  x0_kernel<<<dim3(4, 64), thr, 0, stream>>>(h1, we2t, be2, out + O_X);
  trans_kernel<<<dim3(128, 16), thr, 0, stream>>>(Wm1, wm1t, CHID, CA * CE); // Wm1T
  wpm_kernel<<<dim3(256, 4), thr, 0, stream>>>(wm1t, eo, wpm);
  trans_kernel<<<dim3(16, 4), thr, 0, stream>>>(Wm2, wm2t, CE, CHID);        // Wm2T
  tllists_kernel<<<dim3(8), thr, 0, stream>>>(P, cnttl, listtl);
  xstl_kernel<<<dim3(4096), thr, 0, stream>>>(emb, xstl);
  // time-loop model (factorized, f32)
  l1_kernel<<<dim3(32, 8, 8), thr, 0, stream>>>(wpm, xstl, bm1, cnttl, listtl, 256, hbig);
  l2big_kernel<<<dim3(8, 64), thr, 0, stream>>>(hbig, wm2t, parttl);
  ml_kernel<<<dim3(2048), thr, 0, stream>>>(parttl, bm2, emb, out + O_ML);
  // planning loop: single persistent kernel, relaxed-spin device barriers
  constexpr size_t PLAN_SMEM = 40236 * sizeof(float);  // 160944 B <= 160 KiB
  plan_kernel<<<dim3(256), dim3(512), PLAN_SMEM, stream>>>(
      wpm, wm2t, bm1, P, Ws, bs, Wc, bc, bm2,
      out + O_X, out + O_SL, out + O_VAL, out + O_PA,
      logits, Ibuf, Iup, push, xsp, cntp, listp, part, bar);
  el_kernel<<<dim3(2048), thr, 0, stream>>>(emb, out + O_X, Ws, bs, out + O_EL);
}

// Round 4
// 868.553 us; speedup vs baseline: 3.3350x; 1.3753x over previous
//
#include <hip/hip_runtime.h>

// ---------------------------------------------------------------------------
// Problem constants
// ---------------------------------------------------------------------------
constexpr int CT = 32;      // T
constexpr int CN = 64;      // N
constexpr int CE = 256;     // E = DOBS*V
constexpr int CHID = 1024;
constexpr int CA = 32;      // num options
constexpr int CS = 32;      // planning steps
constexpr int CHP = 8;      // planning horizon
constexpr int TN = CT * CN; // 2048

// d_out float offsets (return order: search_logits, planned_actions, X, value,
// model_loss, embed_loss)
constexpr size_t O_SL  = 0;        // 32*64*32 = 65536
constexpr size_t O_PA  = 65536;    // 64*8     = 512
constexpr size_t O_X   = 66048;    // 64*8*256 = 131072
constexpr size_t O_VAL = 197120;   // 32*64    = 2048
constexpr size_t O_ML  = 199168;   // 32*64*256= 524288
constexpr size_t O_EL  = 723456;   // 32*64    = 2048

// ws byte offsets (~100 MB total)
constexpr size_t B_EMB    = 0;                           // 2 MB   [2048][256] f32
constexpr size_t B_H1     = 2u * 1024 * 1024;            // 256 KB [64][1024]
constexpr size_t B_XS     = B_H1 + 256 * 1024;           // 128 KB [64][512]
constexpr size_t B_PART   = B_XS + 128 * 1024;           // 1 MB   [2 par][64][8][256]
// control block at 3.5 MB
constexpr size_t B_CNT    = 3584u * 1024;                // 32*32 ints
constexpr size_t B_DEC    = B_CNT + 8 * 1024;            // 32 ints
constexpr size_t B_ROW    = B_DEC + 4 * 1024;            // 32*64 ints
constexpr size_t B_LISTS  = B_ROW + 16 * 1024;           // 32*32*64 ints = 256 KB
constexpr size_t B_CNTTL  = B_LISTS + 272 * 1024;        // 32 ints
constexpr size_t B_LISTTL = B_CNTTL + 4 * 1024;          // 32 KB [32][256]
// 32MB+ multi-phase region: We2T (early) -> Wm1T (mid) -> xstl/hbig/parttl/Wm2T
constexpr size_t B_R32    = 4u * 1024 * 1024;
constexpr size_t B_WE2T   = B_R32;                       // 1 MB  (dead after x0)
constexpr size_t B_WM1T   = B_R32;                       // 32 MB (dead after wpm)
constexpr size_t B_XSTL   = B_R32;                       // 4 MB  [2048][512]
constexpr size_t B_HBIG   = B_R32 + 4u * 1024 * 1024;    // 8 MB  [2048][1024]
constexpr size_t B_PARTTL = B_R32 + 12u * 1024 * 1024;   // 16 MB [2048][8][256]
constexpr size_t B_WM2T   = B_R32 + 28u * 1024 * 1024;   // 1 MB  [1024][256]
constexpr size_t B_WPM    = B_R32 + 32u * 1024 * 1024;   // 64 MB [32][512][1024]

// LDS scalar-state indices for fin blocks
constexpr int SI_FLAG = 0, SI_I = 1, SI_PUSH = 2, SI_IUP = 3;

__device__ __forceinline__ void fma4(float4& a, float s, const float4& w) {
  a.x = fmaf(s, w.x, a.x); a.y = fmaf(s, w.y, a.y);
  a.z = fmaf(s, w.z, a.z); a.w = fmaf(s, w.w, a.w);
}

// ---------------------------------------------------------------------------
// init: zero PA+X span of d_out, per-step counters, flags
// ---------------------------------------------------------------------------
__global__ void init_kernel(float* __restrict__ out, int* __restrict__ cnt,
                            int* __restrict__ dec, int* __restrict__ row,
                            int* __restrict__ cnt_tl) {
  int idx = blockIdx.x * 256 + threadIdx.x;
  if (idx < 131584) out[O_PA + idx] = 0.f;  // PA (512) + X (131072) contiguous
  if (idx < CS * CA) cnt[idx] = 0;
  if (idx < CS) dec[idx] = 0;
  if (idx < CS * CN) row[idx] = 0;
  if (idx < CA) cnt_tl[idx] = 0;
}

// ---------------------------------------------------------------------------
// emb[t][n][e] = embed1[obs[t][n][e>>4]][e&15]
// ---------------------------------------------------------------------------
__global__ void emb_kernel(const int* __restrict__ obs, const float* __restrict__ embed1,
                           float* __restrict__ emb) {
  int idx = blockIdx.x * 256 + threadIdx.x;
  int b = idx >> 5, k8 = idx & 31;
  int e0 = k8 * 8;
  int d = e0 >> 4;
  int o = obs[b * 16 + d];
  const float* src = embed1 + o * 16 + (e0 & 15);
  float4 v0 = *(const float4*)src;
  float4 v1 = *(const float4*)(src + 4);
  float* dst = emb + (size_t)b * CE + e0;
  *(float4*)dst = v0;
  *(float4*)(dst + 4) = v1;
}

// ---------------------------------------------------------------------------
// One GRU step with h0 = 0 (only Hs[0] used downstream; Whh provably unused)
// ---------------------------------------------------------------------------
__global__ void h1_kernel(const float* __restrict__ emb, const float* __restrict__ Wih,
                          const float* __restrict__ bih, const float* __restrict__ bhh,
                          float* __restrict__ h1) {
  int t = threadIdx.x, bid = blockIdx.x;   // 256 blocks of (64n x 4j)
  int n = t & 63, j = bid * 4 + (t >> 6);
  const float* x = emb + (size_t)n * CE;   // emb[0] rows
  const float* wr = Wih + (size_t)j * CE;
  const float* wz = Wih + (size_t)(CHID + j) * CE;
  const float* wn = Wih + (size_t)(2 * CHID + j) * CE;
  float ar = 0.f, az = 0.f, an = 0.f;
  #pragma unroll 4
  for (int e = 0; e < CE; ++e) {
    float xe = x[e];
    ar += xe * wr[e]; az += xe * wz[e]; an += xe * wn[e];
  }
  ar += bih[j] + bhh[j];
  az += bih[CHID + j] + bhh[CHID + j];
  float r = 1.f / (1.f + expf(-ar));
  float z = 1.f / (1.f + expf(-az));
  float nn = tanhf(an + bih[2 * CHID + j] + r * bhh[2 * CHID + j]);
  h1[(size_t)n * CHID + j] = (1.f - z) * nn;
}

// ---------------------------------------------------------------------------
// Generic 64x64 tiled transpose: in[R][C] -> out[C][R]
// ---------------------------------------------------------------------------
__global__ void trans_kernel(const float* __restrict__ in, float* __restrict__ out,
                             int R, int C) {
  __shared__ float tile[64][65];
  int tj = threadIdx.x & 63, tg = threadIdx.x >> 6;
  int cb = blockIdx.x * 64, rb = blockIdx.y * 64;
  #pragma unroll
  for (int i = 0; i < 16; ++i) {
    int r = tg * 16 + i;
    tile[r][tj] = in[(size_t)(rb + r) * C + cb + tj];
  }
  __syncthreads();
  #pragma unroll
  for (int i = 0; i < 16; ++i) {
    int c2 = tg * 16 + i;
    out[(size_t)(cb + c2) * R + rb + tj] = tile[tj][c2];
  }
}

// ---------------------------------------------------------------------------
// X[:,0] = h1 @ We2^T + be2   (We2T layout [k][e])
// ---------------------------------------------------------------------------
__global__ void x0_kernel(const float* __restrict__ h1, const float* __restrict__ We2T,
                          const float* __restrict__ be2, float* __restrict__ Xout) {
  int et = blockIdx.x, n = blockIdx.y, t = threadIdx.x;
  int el = t & 63, kq = t >> 6;
  __shared__ float hr[1024];
  __shared__ float sred2[4][64];
  for (int idx = t; idx < 1024; idx += 256) hr[idx] = h1[(size_t)n * CHID + idx];
  __syncthreads();
  int e = et * 64 + el;
  float acc = 0.f;
  for (int k = kq * 256; k < kq * 256 + 256; ++k) acc += hr[k] * We2T[(size_t)k * CE + e];
  sred2[kq][el] = acc;
  __syncthreads();
  if (t < 64) {
    float s2 = sred2[0][t] + sred2[1][t] + sred2[2][t] + sred2[3][t] + be2[et * 64 + t];
    Xout[(size_t)(n * CHP) * CE + et * 64 + t] = s2;
  }
}

// ---------------------------------------------------------------------------
// Factorized model weights:
// Wpm[o][e][j]     = sum_a relu( embed_opt[o][a]) * Wm1[j][a*256+e]
// Wpm[o][256+e][j] = sum_a relu(-embed_opt[o][a]) * Wm1[j][a*256+e]
// ---------------------------------------------------------------------------
__global__ void wpm_kernel(const float* __restrict__ Wm1T, const float* __restrict__ eo,
                           float* __restrict__ Wpm) {
  int e = blockIdx.x, jt = blockIdx.y, t = threadIdx.x;
  int j = jt * 256 + t;
  __shared__ float rp[CA * CA], rm[CA * CA];
  for (int idx = t; idx < CA * CA; idx += 256) {
    float v = eo[idx];
    rp[idx] = fmaxf(v, 0.f);
    rm[idx] = fmaxf(-v, 0.f);
  }
  __syncthreads();
  float w[32];
  #pragma unroll
  for (int a = 0; a < 32; ++a) w[a] = Wm1T[(size_t)(a * 256 + e) * CHID + j];
  for (int o = 0; o < 32; ++o) {
    float sp = 0.f, sm = 0.f;
    #pragma unroll
    for (int a = 0; a < 32; ++a) {
      float wa = w[a];
      sp += rp[o * 32 + a] * wa;
      sm += rm[o * 32 + a] * wa;
    }
    Wpm[((size_t)o * 512 + e) * CHID + j] = sp;
    Wpm[((size_t)o * 512 + 256 + e) * CHID + j] = sm;
  }
}

// ---------------------------------------------------------------------------
// Group time-loop rows by option (list order nondeterministic; results aren't)
// ---------------------------------------------------------------------------
__global__ void tllists_kernel(const int* __restrict__ P, int* __restrict__ cnt_tl,
                               int* __restrict__ list_tl) {
  int b = blockIdx.x * 256 + threadIdx.x;
  if (b >= TN) return;
  int a = P[b];
  int slot = atomicAdd(&cnt_tl[a], 1);
  list_tl[a * 256 + slot] = b;
}

// xs_tl[b][k] = relu(+/- prev[b][k&255]),  prev = emb shifted by one t (wrap)
__global__ void xstl_kernel(const float* __restrict__ emb, float* __restrict__ xs) {
  int idx = blockIdx.x * 256 + threadIdx.x;   // < 2048*512
  int b = idx >> 9, k = idx & 511;
  int e = k & 255;
  int bp = (b < CN) ? (b + (CT - 1) * CN) : (b - CN);
  float v = emb[(size_t)bp * CE + e];
  xs[idx] = (k < 256) ? fmaxf(v, 0.f) : fmaxf(-v, 0.f);
}

// ---------------------------------------------------------------------------
// Time-loop factorized model layer 1:
// h[row][j] = relu( sum_{k<512} xs[row][k] * Wpm[o][k][j] + bm1[j] )
// grid (32 o, 8 j-tiles of 128, z row-group start)
// ---------------------------------------------------------------------------
__global__ __launch_bounds__(256) void l1_kernel(
    const float* __restrict__ Wpm, const float* __restrict__ xs,
    const float* __restrict__ bm1, const int* __restrict__ cnt,
    const int* __restrict__ list, int listStride, float* __restrict__ hout) {
  int o = blockIdx.x, jt = blockIdx.y;
  int c = cnt[o];
  if (c <= 0) return;
  __shared__ __align__(16) float sbuf[8192];
  __shared__ int srows[8];
  int t = threadIdx.x;
  int jl = t & 31, kq = t >> 5;
  int jb = jt * 128;
  const float* wb = Wpm + (size_t)o * (512 * CHID) + jb + jl * 4;
  for (int g = blockIdx.z; g * 8 < c; g += gridDim.z) {
    int base = g * 8;
    int nr = min(8, c - base);
    if (t < 8) srows[t] = (t < nr) ? list[o * listStride + base + t] : -1;
    __syncthreads();
    for (int idx = t; idx < 4096; idx += 256) {
      int row = srows[idx >> 9];
      sbuf[idx] = (row >= 0) ? xs[(size_t)row * 512 + (idx & 511)] : 0.f;
    }
    __syncthreads();
    float4 acc[8];
    #pragma unroll
    for (int r = 0; r < 8; ++r) acc[r] = make_float4(0.f, 0.f, 0.f, 0.f);
    int kbase = kq * 64;
    for (int k4 = 0; k4 < 64; k4 += 4) {
      int k = kbase + k4;
      float4 w0 = *(const float4*)(wb + (size_t)(k + 0) * CHID);
      float4 w1 = *(const float4*)(wb + (size_t)(k + 1) * CHID);
      float4 w2 = *(const float4*)(wb + (size_t)(k + 2) * CHID);
      float4 w3 = *(const float4*)(wb + (size_t)(k + 3) * CHID);
      #pragma unroll
      for (int r = 0; r < 8; ++r) {
        float4 xv = *(const float4*)&sbuf[r * 512 + k];
        fma4(acc[r], xv.x, w0); fma4(acc[r], xv.y, w1);
        fma4(acc[r], xv.z, w2); fma4(acc[r], xv.w, w3);
      }
    }
    __syncthreads();
    #pragma unroll
    for (int r = 0; r < 8; ++r)
      *(float4*)&sbuf[(kq * 8 + r) * 128 + jl * 4] = acc[r];
    __syncthreads();
    for (int idx = t; idx < 1024; idx += 256) {
      int r = idx >> 7, jc = idx & 127;
      float s = 0.f;
      #pragma unroll
      for (int q = 0; q < 8; ++q) s += sbuf[(q * 8 + r) * 128 + jc];
      int row = srows[r];
      if (row >= 0)
        hout[(size_t)row * CHID + jb + jc] = fmaxf(s + bm1[jb + jc], 0.f);
    }
    __syncthreads();
  }
}

// ---------------------------------------------------------------------------
// Time-loop layer 2 partials: part[b][kq][e], 8 k-slices of 128
// grid (8 kq, 64 row-groups of 32), 256 thr (= e)
// ---------------------------------------------------------------------------
__global__ __launch_bounds__(256) void l2big_kernel(const float* __restrict__ h,
    const float* __restrict__ Wm2T, float* __restrict__ part) {
  int kq = blockIdx.x, rg = blockIdx.y, t = threadIdx.x;
  int rb = rg * 32, kb = kq * 128;
  __shared__ __align__(16) float hl[4096];
  for (int idx = t; idx < 4096; idx += 256)
    hl[idx] = h[(size_t)(rb + (idx >> 7)) * CHID + kb + (idx & 127)];
  __syncthreads();
  float acc[32];
  #pragma unroll
  for (int r = 0; r < 32; ++r) acc[r] = 0.f;
  for (int kk = 0; kk < 128; kk += 4) {
    float w0 = Wm2T[(size_t)(kb + kk + 0) * CE + t];
    float w1 = Wm2T[(size_t)(kb + kk + 1) * CE + t];
    float w2 = Wm2T[(size_t)(kb + kk + 2) * CE + t];
    float w3 = Wm2T[(size_t)(kb + kk + 3) * CE + t];
    #pragma unroll
    for (int r = 0; r < 32; ++r) {
      float4 hv = *(const float4*)&hl[r * 128 + kk];
      acc[r] += hv.x * w0 + hv.y * w1 + hv.z * w2 + hv.w * w3;
    }
  }
  #pragma unroll
  for (int r = 0; r < 32; ++r)
    part[((size_t)(rb + r) * 8 + kq) * CE + t] = acc[r];
}

// model_loss = (sum(partials)+bm2 - emb)^2
__global__ void ml_kernel(const float* __restrict__ part, const float* __restrict__ bm2,
                          const float* __restrict__ emb, float* __restrict__ ML) {
  int idx = blockIdx.x * 256 + threadIdx.x;   // < 2048*256
  int b = idx >> 8, e = idx & 255;
  float outv = bm2[e];
  #pragma unroll
  for (int q = 0; q < 8; ++q) outv += part[((size_t)b * 8 + q) * CE + e];
  float d = outv - emb[idx];
  ML[idx] = d * d;
}

// ---------------------------------------------------------------------------
// fin phase (blocks 0..63, n = bid): epilogue of step s-1 + decision of step s.
// Per-n state (I, push, Iup, logits, X copy) lives in block LDS. Cross-block:
// spin row_done[s-1][n]==8 (only if pushed), part_db reads, xs/cnt/lists
// writes, release-fence + dec_done[s] arrive. s==CS: epilogue only.
// ---------------------------------------------------------------------------
__device__ __forceinline__ void fin_phase(
    int s, int n, int t,
    const int* __restrict__ P, const float* __restrict__ Wsg,
    const float* __restrict__ bsg, const float* __restrict__ Wcg,
    const float* __restrict__ bcg, const float* __restrict__ bm2,
    const float* __restrict__ part_db, float* __restrict__ Xout,
    float* __restrict__ SLout, float* __restrict__ VALout,
    float* __restrict__ PAout, float* __restrict__ xsbuf,
    int* __restrict__ cnt, int* __restrict__ lists,
    int* __restrict__ row_done, int* __restrict__ dec_done,
    float* sx, float* sred, float* svals, float* sxtra, int* sint,
    float* logits_s, float* Xlds) {
  // Read-only prefetch, issued BEFORE the spin (inputs never written -> no
  // staleness); latency hides under the dependency wait.
  float wsv = 0.f, bm2v = 0.f, bcv = 0.f, bsv = bsg[0];
  float wcv[32];
  int c2 = t >> 3, g = t & 7;
  if (t < 256) {
    wsv = Wsg[t]; bm2v = bm2[t];
    #pragma unroll
    for (int i = 0; i < 32; ++i) wcv[i] = Wcg[c2 * CE + g * 32 + i];
  }
  if (t < CA) bcv = bcg[t];

  if (s > 0) {
    int push = sint[SI_PUSH];
    if (push) {
      if (t == 0) {
        int* rd = &row_done[(s - 1) * CN + n];
        while (__hip_atomic_load(rd, __ATOMIC_RELAXED, __HIP_MEMORY_SCOPE_AGENT) < 8)
          __builtin_amdgcn_s_sleep(1);
        __builtin_amdgcn_fence(__ATOMIC_ACQUIRE, "agent");
      }
      __syncthreads();
      int Iup = sint[SI_IUP];
      if (t < 256) {
        const float* pb = part_db + (((size_t)((s - 1) & 1) * CN + n) * 8) * CE + t;
        float outv = bm2v;
        #pragma unroll
        for (int q = 0; q < 8; ++q) outv += pb[(size_t)q * CE];
        Xlds[Iup * CE + t] = outv;
        Xout[((size_t)(n * CHP) + Iup) * CE + t] = outv;
        sx[t] = outv;
      }
      if (t == 0) sint[SI_I] = Iup;
    } else {
      int I = sint[SI_I];
      int Inew = (I - 1 > 0) ? I - 1 : 0;
      if (t < 256) sx[t] = Xlds[Inew * CE + t];
      if (t == 0) sint[SI_I] = Inew;
    }
    if (s == CS) return;  // final epilogue only (uniform)
  } else {
    if (t < 256) sx[t] = Xlds[t];
    if (t == 0) sint[SI_I] = 0;
  }
  __syncthreads();
  int I = sint[SI_I];
  if (t < 256) {
    float xv = sx[t];
    float xa = fmaxf(xv, 0.f);
    xsbuf[n * 512 + t] = xa;
    xsbuf[n * 512 + 256 + t] = fmaxf(-xv, 0.f);
    sred[t] = xa * wsv;
  }
  __syncthreads();
  #pragma unroll
  for (int off = 128; off > 0; off >>= 1) {
    if (t < off) sred[t] += sred[t + off];
    __syncthreads();
  }
  if (t == 0) { sxtra[0] = sred[0] + bsv; sint[SI_FLAG] = 1; }
  if (t < 256) {
    float pv = 0.f;
    #pragma unroll 4
    for (int i = 0; i < 32; ++i)
      pv += fmaxf(sx[g * 32 + i], 0.f) * wcv[i];
    pv += __shfl_down(pv, 4, 8);
    pv += __shfl_down(pv, 2, 8);
    pv += __shfl_down(pv, 1, 8);
    if (g == 0) svals[c2] = pv + bcv;
  }
  __syncthreads();
  if (t < CA && logits_s[t] != 0.f) sint[SI_FLAG] = 0;
  __syncthreads();
  int a = P[s * CN + n];
  if (t < CA) {
    float v = svals[t];
    float slv = sint[SI_FLAG] ? sxtra[0] * v : logits_s[t];
    SLout[(size_t)(s * CN + n) * CA + t] = slv;
    logits_s[t] = slv - (t == a ? 1e8f : 0.f);
    if (t == a) {
      VALout[s * CN + n] = slv;
      int pn = (v > 0.f) ? 1 : 0;
      sint[SI_PUSH] = pn;
      PAout[n * CHP + I] = (float)a;
      sint[SI_IUP] = (I + 1 < CHP - 1) ? I + 1 : CHP - 1;
      if (pn) {
        int slot = atomicAdd(&cnt[s * CA + a], 1);
        lists[(s * CA + a) * CN + slot] = n;
      }
    }
  }
  __syncthreads();
  if (t == 0) {
    __builtin_amdgcn_fence(__ATOMIC_RELEASE, "agent");   // flush xs/lists/outputs
    __hip_atomic_fetch_add(&dec_done[s], 1, __ATOMIC_RELAXED, __HIP_MEMORY_SCOPE_AGENT);
  }
  __syncthreads();
}

// ---------------------------------------------------------------------------
// Persistent planning kernel: 256 blocks x 512 threads (1 block/CU, LDS-forced).
// Block (o,jt): Wpm[o][:, jb..jb+128) in 32 NAMED float4 registers per thread
// (SROA-proof: arrays of this size get demoted to scratch — rounds 2/3 bug).
// No global barrier: dec_done / row_done producer-consumer counters.
// ---------------------------------------------------------------------------
#define W_EACH(M) M(0) M(1) M(2) M(3) M(4) M(5) M(6) M(7) M(8) M(9) M(10) \
  M(11) M(12) M(13) M(14) M(15) M(16) M(17) M(18) M(19) M(20) M(21) M(22) \
  M(23) M(24) M(25) M(26) M(27) M(28) M(29) M(30) M(31)
#define WLD(i) float4 W##i = *(const float4*)(wsrc + (size_t)(i) * CHID);
#define WFM(i) { float xv_ = xk[i]; \
  acc.x = fmaf(xv_, W##i.x, acc.x); acc.y = fmaf(xv_, W##i.y, acc.y); \
  acc.z = fmaf(xv_, W##i.z, acc.z); acc.w = fmaf(xv_, W##i.w, acc.w); }

__global__ __launch_bounds__(512, 2) void plan_kernel(
    const float* __restrict__ Wpm, const float* __restrict__ Wm2T,
    const float* __restrict__ bm1g, const int* __restrict__ P,
    const float* Wsg, const float* bsg, const float* Wcg, const float* bcg,
    const float* bm2, float* Xout, float* SLout, float* VALout, float* PAout,
    float* xsbuf, int* cnt, int* lists, int* row_done, int* dec_done,
    float* part_db) {
  extern __shared__ float smem[];
  float* wm2s    = smem;                  // [256 e][130 pad] = 33280
  float* bm1s    = wm2s + 33280;          // 128
  float* red     = bm1s + 128;            // 16*128 = 2048
  float* sh      = red + 2048;            // 128
  float* sxs     = sh + 128;              // 4*512 = 2048
  float* sx      = sxs + 2048;            // 256
  float* sred    = sx + 256;              // 256
  float* svals   = sred + 256;            // 32
  float* sxtra   = svals + 32;            // 4
  int*   sint    = (int*)(sxtra + 4);     // 8
  int*   srows   = sint + 8;              // 4
  int*   rowsAll = srows + 4;             // 64
  float* logits_s= (float*)(rowsAll + 64);// 32
  float* Xlds    = logits_s + 32;         // 2048
  // total 40336 floats = 161344 B <= 160 KiB

  int bid = blockIdx.x, t = threadIdx.x;
  int o = bid >> 3, jt = bid & 7;
  int jl = t & 31, kq = t >> 5;           // kq in [0,16): 32 k each
  int jb = jt * 128;

  // --- prologue: weights resident in NAMED registers + LDS ---
  const float* wsrc = Wpm + ((size_t)o * 512 + (size_t)kq * 32) * CHID + jb + jl * 4;
  W_EACH(WLD)
  for (int idx = t; idx < 128 * 256; idx += 512) {
    int e = idx & 255, j = idx >> 8;
    wm2s[e * 130 + j] = Wm2T[(size_t)(jb + j) * CE + e];
  }
  if (t < 128) bm1s[t] = bm1g[jb + t];
  if (bid < CN) {
    for (int idx = t; idx < CHP * CE; idx += 512)
      Xlds[idx] = Xout[(size_t)bid * (CHP * CE) + idx];
    if (t < 32) logits_s[t] = 0.f;
    if (t < 8) sint[t] = 0;
  }
  __syncthreads();

  if (bid < CN)
    fin_phase(0, bid, t, P, Wsg, bsg, Wcg, bcg, bm2, part_db, Xout, SLout,
              VALout, PAout, xsbuf, cnt, lists, row_done, dec_done,
              sx, sred, svals, sxtra, sint, logits_s, Xlds);

  for (int s = 0; s < CS; ++s) {
    // --- phase A: wait decisions, run l1+l2 for this option's pushed rows ---
    if (t == 0) {
      while (__hip_atomic_load(&dec_done[s], __ATOMIC_RELAXED,
                               __HIP_MEMORY_SCOPE_AGENT) < CN)
        __builtin_amdgcn_s_sleep(2);
      __builtin_amdgcn_fence(__ATOMIC_ACQUIRE, "agent");
    }
    __syncthreads();
    int c = cnt[s * CA + o];
    for (int base = 0; base < c; base += 4) {
      int nb2 = min(4, c - base);
      if (t < 4) srows[t] = (t < nb2) ? lists[(s * CA + o) * CN + base + t] : -1;
      __syncthreads();
      for (int idx = t; idx < 2048; idx += 512) {
        int row = srows[idx >> 9];
        sxs[idx] = (row >= 0) ? xsbuf[row * 512 + (idx & 511)] : 0.f;
      }
      if (t < nb2) rowsAll[base + t] = srows[t];
      __syncthreads();
      for (int r = 0; r < nb2; ++r) {
        float4 acc; acc.x = acc.y = acc.z = acc.w = 0.f;
        const float* xk = sxs + r * 512 + kq * 32;
        W_EACH(WFM)
        *(float4*)&red[kq * 128 + jl * 4] = acc;
        __syncthreads();
        if (t < 128) {
          float s1 = 0.f;
          #pragma unroll
          for (int q = 0; q < 16; ++q) s1 += red[q * 128 + t];
          sh[t] = fmaxf(s1 + bm1s[t], 0.f);
        }
        __syncthreads();
        if (t < 256) {
          float a2 = 0.f;
          #pragma unroll 16
          for (int jj = 0; jj < 64; ++jj) {
            float2 hv = *(const float2*)&sh[jj * 2];
            float2 wv = *(const float2*)&wm2s[t * 130 + jj * 2];
            a2 = fmaf(hv.x, wv.x, fmaf(hv.y, wv.y, a2));
          }
          int row = srows[r];
          part_db[(((size_t)(s & 1) * CN + row) * 8 + jt) * CE + t] = a2;
        }
        __syncthreads();
      }
    }
    __syncthreads();
    if (t == 0 && c > 0) {
      __builtin_amdgcn_fence(__ATOMIC_RELEASE, "agent");  // flush part writes
      for (int r = 0; r < c; ++r)
        __hip_atomic_fetch_add(&row_done[s * CN + rowsAll[r]], 1,
                               __ATOMIC_RELAXED, __HIP_MEMORY_SCOPE_AGENT);
    }
    // --- fin: epilogue(s) + decision(s+1) ---
    if (bid < CN)
      fin_phase(s + 1, bid, t, P, Wsg, bsg, Wcg, bcg, bm2, part_db, Xout, SLout,
                VALout, PAout, xsbuf, cnt, lists, row_done, dec_done,
                sx, sred, svals, sxtra, sint, logits_s, Xlds);
  }
}

// ---------------------------------------------------------------------------
// embed_loss
// ---------------------------------------------------------------------------
__global__ void el_kernel(const float* __restrict__ emb, const float* __restrict__ Xout,
                          const float* __restrict__ Ws, const float* __restrict__ bsp,
                          float* __restrict__ EL) {
  int tn = blockIdx.x;
  int n = tn & 63;
  int t = threadIdx.x, h = t >> 5, l = t & 31;
  const float* er = emb + (size_t)tn * CE;
  const float* xr = Xout + ((size_t)(n * CHP) + h) * CE;
  float pd = 0.f, px = 0.f, pe = 0.f, ps = 0.f;
  #pragma unroll
  for (int i = 0; i < 8; ++i) {
    int e = l * 8 + i;
    float ev = er[e], xv2 = xr[e];
    pd += ev * xv2; px += xv2 * xv2; pe += ev * ev; ps += fmaxf(ev, 0.f) * Ws[e];
  }
  #pragma unroll
  for (int off = 16; off > 0; off >>= 1) {
    pd += __shfl_down(pd, off, 32);
    px += __shfl_down(px, off, 32);
    pe += __shfl_down(pe, off, 32);
    ps += __shfl_down(ps, off, 32);
  }
  __shared__ float sdot[8], snx[8];
  __shared__ float sne, ssh;
  if (l == 0) {
    sdot[h] = pd;
    snx[h] = sqrtf(px);
    if (h == 0) { sne = sqrtf(pe); ssh = ps + bsp[0]; }
  }
  __syncthreads();
  if (t == 0) {
    const float eps = 1e-8f;
    float y[8];
    float m = -1e30f;
    #pragma unroll
    for (int hh = 0; hh < 8; ++hh) {
      float cs = sdot[hh] / ((sne + eps) * (snx[hh] + eps));
      y[hh] = ssh * cs;
      m = fmaxf(m, y[hh]);
    }
    float sum = 0.f;
    #pragma unroll
    for (int hh = 0; hh < 8; ++hh) sum += expf(y[hh] - m);
    float lse = logf(sum);
    float el = 0.f;
    #pragma unroll
    for (int hh = 0; hh < 8; ++hh) {
      float lp = y[hh] - m - lse;
      el += expf(lp) * lp;
    }
    EL[tn] = el;
  }
}

// ---------------------------------------------------------------------------
extern "C" void kernel_launch(void* const* d_in, const int* in_sizes, int n_in,
                              void* d_out, int out_size, void* d_ws, size_t ws_size,
                              hipStream_t stream) {
  (void)in_sizes; (void)n_in; (void)out_size; (void)ws_size;
  const int*   obs    = (const int*)d_in[0];
  const int*   P      = (const int*)d_in[1];
  const float* embed1 = (const float*)d_in[2];
  const float* Wih    = (const float*)d_in[3];
  // d_in[4] = Whh: provably unused (h0 = 0 and only Hs[0] is consumed)
  const float* bih    = (const float*)d_in[5];
  const float* bhh    = (const float*)d_in[6];
  const float* We2    = (const float*)d_in[7];
  const float* be2    = (const float*)d_in[8];
  const float* Ws     = (const float*)d_in[9];
  const float* bs     = (const float*)d_in[10];
  const float* Wc     = (const float*)d_in[11];
  const float* bc     = (const float*)d_in[12];
  const float* Wm1    = (const float*)d_in[13];
  const float* bm1    = (const float*)d_in[14];
  const float* Wm2    = (const float*)d_in[15];
  const float* bm2    = (const float*)d_in[16];
  const float* eo     = (const float*)d_in[17];
  float* out = (float*)d_out;
  char*  ws  = (char*)d_ws;

  float* emb    = (float*)(ws + B_EMB);
  float* h1     = (float*)(ws + B_H1);
  float* xsp    = (float*)(ws + B_XS);
  float* part_db= (float*)(ws + B_PART);
  int*   cntp   = (int*)(ws + B_CNT);
  int*   decd   = (int*)(ws + B_DEC);
  int*   rowd   = (int*)(ws + B_ROW);
  int*   listp  = (int*)(ws + B_LISTS);
  int*   cnttl  = (int*)(ws + B_CNTTL);
  int*   listtl = (int*)(ws + B_LISTTL);
  float* we2t   = (float*)(ws + B_WE2T);
  float* wm1t   = (float*)(ws + B_WM1T);
  float* xstl   = (float*)(ws + B_XSTL);
  float* hbig   = (float*)(ws + B_HBIG);
  float* parttl = (float*)(ws + B_PARTTL);
  float* wm2t   = (float*)(ws + B_WM2T);
  float* wpm    = (float*)(ws + B_WPM);

  dim3 thr(256);
  init_kernel<<<dim3(514), thr, 0, stream>>>(out, cntp, decd, rowd, cnttl);
  emb_kernel<<<dim3(256), thr, 0, stream>>>(obs, embed1, emb);
  h1_kernel<<<dim3(256), thr, 0, stream>>>(emb, Wih, bih, bhh, h1);
  trans_kernel<<<dim3(16, 4), thr, 0, stream>>>(We2, we2t, CE, CHID);        // We2T
  x0_kernel<<<dim3(4, 64), thr, 0, stream>>>(h1, we2t, be2, out + O_X);
  trans_kernel<<<dim3(128, 16), thr, 0, stream>>>(Wm1, wm1t, CHID, CA * CE); // Wm1T
  wpm_kernel<<<dim3(256, 4), thr, 0, stream>>>(wm1t, eo, wpm);
  trans_kernel<<<dim3(16, 4), thr, 0, stream>>>(Wm2, wm2t, CE, CHID);        // Wm2T
  tllists_kernel<<<dim3(8), thr, 0, stream>>>(P, cnttl, listtl);
  xstl_kernel<<<dim3(4096), thr, 0, stream>>>(emb, xstl);
  // time-loop model (factorized, f32)
  l1_kernel<<<dim3(32, 8, 8), thr, 0, stream>>>(wpm, xstl, bm1, cnttl, listtl, 256, hbig);
  l2big_kernel<<<dim3(8, 64), thr, 0, stream>>>(hbig, wm2t, parttl);
  ml_kernel<<<dim3(2048), thr, 0, stream>>>(parttl, bm2, emb, out + O_ML);
  // planning loop: persistent kernel, producer/consumer flags (no global barrier)
  constexpr size_t PLAN_SMEM = 40336 * sizeof(float);  // 161344 B <= 160 KiB
  plan_kernel<<<dim3(256), dim3(512), PLAN_SMEM, stream>>>(
      wpm, wm2t, bm1, P, Ws, bs, Wc, bc, bm2,
      out + O_X, out + O_SL, out + O_VAL, out + O_PA,
      xsp, cntp, listp, rowd, decd, part_db);
  el_kernel<<<dim3(2048), thr, 0, stream>>>(emb, out + O_X, Ws, bs, out + O_EL);
}